// Round 5
// baseline (2458.360 us; speedup 1.0000x reference)
//
#include <hip/hip_runtime.h>
#include <stdint.h>

#define T_LEN 8196
#define LOG2E 1.4426950408889634f
#define LN2   0.6931471805599453f
#define INF2  1.4426950e10f   /* 1e10 * log2(e): INF in base-2-scaled units */
#define PD_LD 2128            /* padded D row stride: 64 left + 2048 + 16 right */
#define PD_OFF 64

// ---------------------------------------------------------------- helpers
__device__ __forceinline__ float fexp2(float x) {
#if __has_builtin(__builtin_amdgcn_exp2f)
    return __builtin_amdgcn_exp2f(x);
#else
    return __expf(x * LN2);
#endif
}
__device__ __forceinline__ float flog2(float x) {
#if __has_builtin(__builtin_amdgcn_logf)
    return __builtin_amdgcn_logf(x);   // v_log_f32 is base-2
#else
    return __logf(x) * LOG2E;
#endif
}
// softmin in base-2-scaled units: out = m - log2(2^(m-a)+2^(m-b)+2^(m-c))
__device__ __forceinline__ float softmin2(float a, float b, float c) {
    float m = fminf(fminf(a, b), c);
    float s = fexp2(m - a) + fexp2(m - b) + fexp2(m - c);
    return m - flog2(s);
}
__device__ __forceinline__ float sigm(float x) { return 1.0f / (1.0f + __expf(-x)); }
__device__ __forceinline__ float tanh_f(float x) {
    x = fminf(fmaxf(x, -15.0f), 15.0f);
    float e = __expf(2.0f * x);
    return (e - 1.0f) / (e + 1.0f);
}

// ------------------------------------------- prep: transpose weights
// wt layout (floats): Wih1^T [72][384] @0, Whh1^T [128][384] @27648,
//                     Wih2^T [128][384] @76800, Whh2^T [128][384] @125952
__global__ void k_prep(const float* __restrict__ Wih1, const float* __restrict__ Whh1,
                       const float* __restrict__ Wih2, const float* __restrict__ Whh2,
                       float* __restrict__ wt) {
    int gid = blockIdx.x * 256 + threadIdx.x;
    if (gid >= 175104) return;
    if (gid < 27648) {
        int k = gid / 384, g = gid % 384;
        wt[gid] = Wih1[g * 72 + k];
    } else if (gid < 76800) {
        int r = gid - 27648; int k = r / 384, g = r % 384;
        wt[gid] = Whh1[g * 128 + k];
    } else if (gid < 125952) {
        int r = gid - 76800; int k = r / 384, g = r % 384;
        wt[gid] = Wih2[g * 128 + k];
    } else {
        int r = gid - 125952; int k = r / 384, g = r % 384;
        wt[gid] = Whh2[g * 128 + k];
    }
}

// ------------------------------------------- GRU features (unchanged)
__global__ __launch_bounds__(256)
void k_gru(const float* __restrict__ X, const float* __restrict__ Y,
           const float* __restrict__ wt,
           const float* __restrict__ bih1, const float* __restrict__ bhh1,
           const float* __restrict__ bih2, const float* __restrict__ bhh2,
           const float* __restrict__ W1, const float* __restrict__ b1,
           float* __restrict__ fbuf) {
    __shared__ __align__(16) float xb[72 * 20];
    __shared__ __align__(16) float h1l[128 * 20];
    __shared__ __align__(16) float h2l[128 * 20];

    const int tid = threadIdx.x;
    const int u = tid & 127;
    const int w0 = (tid >> 7) * 8;
    const int bx = blockIdx.x;
    const int seq = bx >> 7;
    const int wbase = (bx & 127) << 4;
    const float* xp = seq ? Y : X;

    const float* wih1 = wt;
    const float* whh1 = wt + 27648;
    const float* wih2 = wt + 76800;
    const float* whh2 = wt + 125952;

    const float br1  = bih1[u] + bhh1[u];
    const float bz1  = bih1[128 + u] + bhh1[128 + u];
    const float bni1 = bih1[256 + u];
    const float bnh1 = bhh1[256 + u];
    const float br2  = bih2[u] + bhh2[u];
    const float bz2  = bih2[128 + u] + bhh2[128 + u];
    const float bni2 = bih2[256 + u];
    const float bnh2 = bhh2[256 + u];

    float h1r[8], h2r[8];
#pragma unroll
    for (int j = 0; j < 8; ++j) { h1r[j] = 0.f; h2r[j] = 0.f; }
    for (int e = tid; e < 128 * 20; e += 256) { h1l[e] = 0.f; h2l[e] = 0.f; }
    __syncthreads();

    for (int t = 0; t < 8; ++t) {
        for (int e = tid; e < 72 * 16; e += 256) {
            int k = e >> 4, w = e & 15;
            int jj = k / 3, c = k - jj * 3;
            xb[k * 20 + w] = xp[jj * (3 * T_LEN) + c * T_LEN + ((wbase + w) << 2) + t];
        }
        __syncthreads();

        float ar[8], az[8], ai[8], ah[8];
#pragma unroll
        for (int j = 0; j < 8; ++j) { ar[j] = br1; az[j] = bz1; ai[j] = bni1; ah[j] = bnh1; }
        for (int k = 0; k < 72; ++k) {
            float wr = wih1[k * 384 + u];
            float wz = wih1[k * 384 + 128 + u];
            float wn = wih1[k * 384 + 256 + u];
            const float4 x0 = *(const float4*)&xb[k * 20 + w0];
            const float4 x1 = *(const float4*)&xb[k * 20 + w0 + 4];
            float xv[8] = {x0.x, x0.y, x0.z, x0.w, x1.x, x1.y, x1.z, x1.w};
#pragma unroll
            for (int j = 0; j < 8; ++j) {
                ar[j] = fmaf(wr, xv[j], ar[j]);
                az[j] = fmaf(wz, xv[j], az[j]);
                ai[j] = fmaf(wn, xv[j], ai[j]);
            }
        }
        for (int k = 0; k < 128; ++k) {
            float wr = whh1[k * 384 + u];
            float wz = whh1[k * 384 + 128 + u];
            float wn = whh1[k * 384 + 256 + u];
            const float4 x0 = *(const float4*)&h1l[k * 20 + w0];
            const float4 x1 = *(const float4*)&h1l[k * 20 + w0 + 4];
            float xv[8] = {x0.x, x0.y, x0.z, x0.w, x1.x, x1.y, x1.z, x1.w};
#pragma unroll
            for (int j = 0; j < 8; ++j) {
                ar[j] = fmaf(wr, xv[j], ar[j]);
                az[j] = fmaf(wz, xv[j], az[j]);
                ah[j] = fmaf(wn, xv[j], ah[j]);
            }
        }
        __syncthreads();
#pragma unroll
        for (int j = 0; j < 8; ++j) {
            float r = sigm(ar[j]);
            float z = sigm(az[j]);
            float n = tanh_f(ai[j] + r * ah[j]);
            h1r[j] = (1.f - z) * n + z * h1r[j];
        }
#pragma unroll
        for (int j = 0; j < 8; ++j) h1l[u * 20 + w0 + j] = h1r[j];
        __syncthreads();

#pragma unroll
        for (int j = 0; j < 8; ++j) { ar[j] = br2; az[j] = bz2; ai[j] = bni2; ah[j] = bnh2; }
        for (int k = 0; k < 128; ++k) {
            float wr = wih2[k * 384 + u];
            float wz = wih2[k * 384 + 128 + u];
            float wn = wih2[k * 384 + 256 + u];
            const float4 x0 = *(const float4*)&h1l[k * 20 + w0];
            const float4 x1 = *(const float4*)&h1l[k * 20 + w0 + 4];
            float xv[8] = {x0.x, x0.y, x0.z, x0.w, x1.x, x1.y, x1.z, x1.w};
#pragma unroll
            for (int j = 0; j < 8; ++j) {
                ar[j] = fmaf(wr, xv[j], ar[j]);
                az[j] = fmaf(wz, xv[j], az[j]);
                ai[j] = fmaf(wn, xv[j], ai[j]);
            }
        }
        for (int k = 0; k < 128; ++k) {
            float wr = whh2[k * 384 + u];
            float wz = whh2[k * 384 + 128 + u];
            float wn = whh2[k * 384 + 256 + u];
            const float4 x0 = *(const float4*)&h2l[k * 20 + w0];
            const float4 x1 = *(const float4*)&h2l[k * 20 + w0 + 4];
            float xv[8] = {x0.x, x0.y, x0.z, x0.w, x1.x, x1.y, x1.z, x1.w};
#pragma unroll
            for (int j = 0; j < 8; ++j) {
                ar[j] = fmaf(wr, xv[j], ar[j]);
                az[j] = fmaf(wz, xv[j], az[j]);
                ah[j] = fmaf(wn, xv[j], ah[j]);
            }
        }
        __syncthreads();
#pragma unroll
        for (int j = 0; j < 8; ++j) {
            float r = sigm(ar[j]);
            float z = sigm(az[j]);
            float n = tanh_f(ai[j] + r * ah[j]);
            h2r[j] = (1.f - z) * n + z * h2r[j];
        }
#pragma unroll
        for (int j = 0; j < 8; ++j) h2l[u * 20 + w0 + j] = h2r[j];
        __syncthreads();
    }

    for (int idx = tid; idx < 16 * 30; idx += 256) {
        int w = idx / 30, ff = idx - w * 30;
        float acc = b1[ff];
        for (int k = 0; k < 128; ++k) acc = fmaf(h2l[k * 20 + w], W1[ff * 128 + k], acc);
        fbuf[(seq * 2048 + wbase + w) * 32 + ff] = acc;
    }
}

// ------------------------------------------- pairwise sqdist -> padded, base-2 scaled
__global__ __launch_bounds__(256)
void k_pair(const float* __restrict__ fbuf, float* __restrict__ Dp) {
    __shared__ float f1t[64 * 33];
    __shared__ float f2t[64 * 33];
    const int tid = threadIdx.x;
    const int i0 = blockIdx.y * 64, j0 = blockIdx.x * 64;
    for (int e = tid; e < 64 * 32; e += 256) {
        int r = e >> 5, c = e & 31;
        f1t[r * 33 + c] = fbuf[(i0 + r) * 32 + c];
        f2t[r * 33 + c] = fbuf[(2048 + j0 + r) * 32 + c];
    }
    __syncthreads();
    const int tx = tid & 15, ty = tid >> 4;
    float acc[4][4];
#pragma unroll
    for (int r = 0; r < 4; ++r)
#pragma unroll
        for (int c = 0; c < 4; ++c) acc[r][c] = 0.f;
    for (int k = 0; k < 30; ++k) {
        float a[4], b[4];
#pragma unroll
        for (int r = 0; r < 4; ++r) a[r] = f1t[(ty * 4 + r) * 33 + k];
#pragma unroll
        for (int c = 0; c < 4; ++c) b[c] = f2t[(tx * 4 + c) * 33 + k];
#pragma unroll
        for (int r = 0; r < 4; ++r)
#pragma unroll
            for (int c = 0; c < 4; ++c) {
                float d = a[r] - b[c];
                acc[r][c] = fmaf(d, d, acc[r][c]);
            }
    }
#pragma unroll
    for (int r = 0; r < 4; ++r) {
        float4 v = make_float4(acc[r][0] * LOG2E, acc[r][1] * LOG2E,
                               acc[r][2] * LOG2E, acc[r][3] * LOG2E);
        *(float4*)&Dp[(size_t)(i0 + ty * 4 + r) * PD_LD + PD_OFF + j0 + tx * 4] = v;
    }
}

// ------------------------------------------- softDTW wavefront
// 2 blocks x 8 waves x 64 lanes; band B = b*8+w owns rows B*128+2*lane(+1).
// At step t lane i computes col j = t - i for both rows. Cross-lane: shfl_up.
// Intra-block band handoff: full-size LDS value array + release/acquire
// workgroup progress counter (ds latency ~120 cyc vs ~900 global).
// Single global boundary (b0.w7 -> b1.w0): packed (tag<<32|f32) relaxed
// agent atomic-exchange publish; consumer polls in BATCHED rounds (8 loads,
// one wait, check all) -- R4's serial per-element re-polls (~8x900 cyc/batch)
// were the residual bottleneck.
#define DTW_BATCH(CUR, NXT, T0)                                                  \
  {                                                                              \
    const int t0 = (T0);                                                         \
    _Pragma("unroll")                                                            \
    for (int u = 0; u < 8; ++u) {   /* prefetch next batch's D (padded rows) */  \
        int jj = min(t0 + 8 + u - lane, 2063);                                   \
        NXT[0][u] = rowp0[jj];                                                   \
        NXT[1][u] = rowp1[jj];                                                   \
    }                                                                            \
    uint64_t pvg[8];                                                             \
    if (glb_in) {                                                                \
        _Pragma("unroll")                                                        \
        for (int u = 0; u < 8; ++u) {   /* speculative next-batch loads */       \
            int jc = min(t0 + 8 + u, 2047);                                      \
            pvg[u] = __hip_atomic_load(&bndG[jc], __ATOMIC_RELAXED,              \
                                       __HIP_MEMORY_SCOPE_AGENT);                \
        }                                                                        \
    }                                                                            \
    _Pragma("unroll")                                                            \
    for (int u = 0; u < 8; ++u) {                                                \
        const int t = t0 + u;                                                    \
        const int j = t - lane;                                                  \
        const bool valid = (j >= 0) && (j < 2048);                               \
        float upA, dgA;                                                          \
        if (top) { upA = INF2; dgA = (j == 0) ? 0.f : INF2; }                    \
        else { upA = bnd_cur[u]; dgA = (u == 0) ? bnd_carry : bnd_cur[u - 1]; }  \
        if (lane > 0) { upA = s1; dgA = s1p; }                                   \
        float vA = valid ? (CUR[0][u] + softmin2(dgA, upA, L0)) : INF2;          \
        float vB = valid ? (CUR[1][u] + softmin2(L0, vA, L1)) : INF2;            \
        s1p = s1;                                                                \
        s1 = __shfl_up(vB, 1);                                                   \
        L0 = vA; L1 = vB;                                                        \
        if (lane == 63 && valid) {                                               \
            if (lds_out) {                                                       \
                ringOut[j] = vB;                                                 \
            } else if (glb_out) {                                                \
                uint64_t pk = ((uint64_t)(uint32_t)j << 32) |                    \
                              (uint64_t)__float_as_uint(vB);                     \
                (void)__hip_atomic_exchange(&bndG[j], pk, __ATOMIC_RELAXED,      \
                                            __HIP_MEMORY_SCOPE_AGENT);           \
            } else if (j == 2047) { res = vB; }                                  \
        }                                                                        \
    }                                                                            \
    bnd_carry = bnd_cur[7];                                                      \
    if (lds_out && lane == 63)                                                   \
        __hip_atomic_store(progOut, t0 + 8, __ATOMIC_RELEASE,                    \
                           __HIP_MEMORY_SCOPE_WORKGROUP);                        \
    if (lds_in) {                                                                \
        const int need = min(t0 + 15, 2047) + 64;                                \
        while (__hip_atomic_load(progIn, __ATOMIC_ACQUIRE,                       \
                                 __HIP_MEMORY_SCOPE_WORKGROUP) < need)           \
            __builtin_amdgcn_s_sleep(1);                                         \
        _Pragma("unroll")                                                        \
        for (int u = 0; u < 8; ++u) bnd_cur[u] = ringIn[min(t0 + 8 + u, 2047)];  \
    } else if (glb_in) {                                                         \
        bool again = false;                                                      \
        _Pragma("unroll")                                                        \
        for (int u = 0; u < 8; ++u) {                                            \
            int jc = min(t0 + 8 + u, 2047);                                      \
            if ((uint32_t)(pvg[u] >> 32) != (uint32_t)jc) again = true;          \
        }                                                                        \
        while (again) {   /* batched re-poll rounds: 8 loads, one wait */        \
            __builtin_amdgcn_s_sleep(2);                                         \
            _Pragma("unroll")                                                    \
            for (int u = 0; u < 8; ++u) {                                        \
                int jc = min(t0 + 8 + u, 2047);                                  \
                pvg[u] = __hip_atomic_load(&bndG[jc], __ATOMIC_RELAXED,          \
                                           __HIP_MEMORY_SCOPE_AGENT);            \
            }                                                                    \
            again = false;                                                       \
            _Pragma("unroll")                                                    \
            for (int u = 0; u < 8; ++u) {                                        \
                int jc = min(t0 + 8 + u, 2047);                                  \
                if ((uint32_t)(pvg[u] >> 32) != (uint32_t)jc) again = true;      \
            }                                                                    \
        }                                                                        \
        _Pragma("unroll")                                                        \
        for (int u = 0; u < 8; ++u)                                              \
            bnd_cur[u] = __uint_as_float((uint32_t)pvg[u]);                      \
    }                                                                            \
  }

__global__ __launch_bounds__(512)
void k_dtw(const float* __restrict__ Dp, uint64_t* bndG, float* __restrict__ out) {
    __shared__ float ldsV[7 * 2048];   // 57,344 B: full per-boundary value arrays
    __shared__ int   ldsP[7];          // progress counters ("cols < p published... as t+1")

    const int tid  = threadIdx.x;
    const int w    = tid >> 6;
    const int lane = tid & 63;
    const int b    = blockIdx.x;
    const int B    = b * 8 + w;        // band 0..15

    if (tid < 7) ldsP[tid] = 0;
    __syncthreads();

    const bool top     = (B == 0);
    const bool lds_in  = (w > 0);
    const bool glb_in  = (w == 0 && b == 1);
    const bool lds_out = (w < 7);
    const bool glb_out = (w == 7 && b == 0);

    float* ringIn  = ldsV + (w > 0 ? (w - 1) * 2048 : 0);
    float* ringOut = ldsV + (w < 7 ? w * 2048 : 0);
    int*   progIn  = ldsP + (w > 0 ? w - 1 : 0);
    int*   progOut = ldsP + (w < 7 ? w : 0);

    const int r0 = B * 128 + 2 * lane;
    const float* rowp0 = Dp + (size_t)r0 * PD_LD + PD_OFF;
    const float* rowp1 = rowp0 + PD_LD;

    float L0 = INF2, L1 = INF2;       // left values (col j-1) for rows rA,rB
    float s1 = INF2, s1p = INF2;      // shfl history of lane-1's rB values
    float bnd_carry = INF2;
    float res = 0.f;
    float bnd_cur[8];
#pragma unroll
    for (int u = 0; u < 8; ++u) bnd_cur[u] = INF2;

    float dA[2][8], dB[2][8];
#pragma unroll
    for (int u = 0; u < 8; ++u) {     // preload batch 0 (left pad covers j<0)
        int jj = u - lane;
        dA[0][u] = rowp0[jj];
        dA[1][u] = rowp1[jj];
    }

    // pre-loop boundary verify for cols 0..7
    if (lds_in) {
        while (__hip_atomic_load(progIn, __ATOMIC_ACQUIRE,
                                 __HIP_MEMORY_SCOPE_WORKGROUP) < 71)
            __builtin_amdgcn_s_sleep(1);
#pragma unroll
        for (int u = 0; u < 8; ++u) bnd_cur[u] = ringIn[u];
    } else if (glb_in) {
        uint64_t pv[8];
        bool again = true;
        while (again) {
#pragma unroll
            for (int u = 0; u < 8; ++u)
                pv[u] = __hip_atomic_load(&bndG[u], __ATOMIC_RELAXED,
                                          __HIP_MEMORY_SCOPE_AGENT);
            again = false;
#pragma unroll
            for (int u = 0; u < 8; ++u)
                if ((uint32_t)(pv[u] >> 32) != (uint32_t)u) again = true;
            if (again) __builtin_amdgcn_s_sleep(2);
        }
#pragma unroll
        for (int u = 0; u < 8; ++u) bnd_cur[u] = __uint_as_float((uint32_t)pv[u]);
    }

    // 264 batches of 8 steps cover t = 0 .. 2111 (need t up to 2110)
    for (int bt = 0; bt < 264; bt += 2) {
        DTW_BATCH(dA, dB, bt * 8);
        DTW_BATCH(dB, dA, (bt + 1) * 8);
    }

    if (b == 1 && w == 7 && lane == 63) out[0] = res * LN2;  // back to base-e
}

// ------------------------------------------- launch
extern "C" void kernel_launch(void* const* d_in, const int* in_sizes, int n_in,
                              void* d_out, int out_size, void* d_ws, size_t ws_size,
                              hipStream_t stream) {
    const float* X    = (const float*)d_in[0];
    const float* Y    = (const float*)d_in[1];
    const float* Wih1 = (const float*)d_in[2];
    const float* Whh1 = (const float*)d_in[3];
    const float* bih1 = (const float*)d_in[4];
    const float* bhh1 = (const float*)d_in[5];
    const float* Wih2 = (const float*)d_in[6];
    const float* Whh2 = (const float*)d_in[7];
    const float* bih2 = (const float*)d_in[8];
    const float* bhh2 = (const float*)d_in[9];
    const float* W1   = (const float*)d_in[10];
    const float* b1   = (const float*)d_in[11];
    float* out = (float*)d_out;

    // Layout (floats). wt overlaps Dp's tail: wt is dead after k_gru, and
    // k_pair (which overwrites all of Dp) runs after k_gru. ~18.0 MB total.
    float* ws   = (float*)d_ws;
    float* fbuf = ws;                            // 131072 floats
    uint64_t* bndG = (uint64_t*)(ws + 131072);   // 2048 u64 = 4096 floats
    float* Dp   = ws + 131072 + 4096;            // 2048*2128 = 4358144 floats
    float* wt   = Dp + 4358144 - 175104;         // overlapped tail

    k_prep<<<684, 256, 0, stream>>>(Wih1, Whh1, Wih2, Whh2, wt);
    k_gru<<<256, 256, 0, stream>>>(X, Y, wt, bih1, bhh1, bih2, bhh2, W1, b1, fbuf);
    k_pair<<<dim3(32, 32), 256, 0, stream>>>(fbuf, Dp);
    k_dtw<<<2, 512, 0, stream>>>(Dp, bndG, out);
}

// Round 6
// 1399.075 us; speedup vs baseline: 1.7571x; 1.7571x over previous
//
#include <hip/hip_runtime.h>
#include <stdint.h>

#define T_LEN 8196
#define LOG2E 1.4426950408889634f
#define LN2   0.6931471805599453f
#define INF2  1.4426950e10f   /* 1e10 * log2(e): INF in base-2-scaled units */
#define PD_LD 2080            /* padded E row stride: 16 left + 2048 + 16 right */
#define PD_OFF 16

// ---------------------------------------------------------------- helpers
__device__ __forceinline__ float fexp2(float x) {
#if __has_builtin(__builtin_amdgcn_exp2f)
    return __builtin_amdgcn_exp2f(x);
#else
    return __expf(x * LN2);
#endif
}
__device__ __forceinline__ float flog2(float x) {
#if __has_builtin(__builtin_amdgcn_logf)
    return __builtin_amdgcn_logf(x);   // v_log_f32 is base-2
#else
    return __logf(x) * LOG2E;
#endif
}
__device__ __forceinline__ float sigm(float x) { return 1.0f / (1.0f + __expf(-x)); }
__device__ __forceinline__ float tanh_f(float x) {
    x = fminf(fmaxf(x, -15.0f), 15.0f);
    float e = __expf(2.0f * x);
    return (e - 1.0f) / (e + 1.0f);
}

// ------------------------------------------- prep: transpose weights
__global__ void k_prep(const float* __restrict__ Wih1, const float* __restrict__ Whh1,
                       const float* __restrict__ Wih2, const float* __restrict__ Whh2,
                       float* __restrict__ wt) {
    int gid = blockIdx.x * 256 + threadIdx.x;
    if (gid >= 175104) return;
    if (gid < 27648) {
        int k = gid / 384, g = gid % 384;
        wt[gid] = Wih1[g * 72 + k];
    } else if (gid < 76800) {
        int r = gid - 27648; int k = r / 384, g = r % 384;
        wt[gid] = Whh1[g * 128 + k];
    } else if (gid < 125952) {
        int r = gid - 76800; int k = r / 384, g = r % 384;
        wt[gid] = Wih2[g * 128 + k];
    } else {
        int r = gid - 125952; int k = r / 384, g = r % 384;
        wt[gid] = Whh2[g * 128 + k];
    }
}

// ------------------------------------------- GRU features (unchanged)
__global__ __launch_bounds__(256)
void k_gru(const float* __restrict__ X, const float* __restrict__ Y,
           const float* __restrict__ wt,
           const float* __restrict__ bih1, const float* __restrict__ bhh1,
           const float* __restrict__ bih2, const float* __restrict__ bhh2,
           const float* __restrict__ W1, const float* __restrict__ b1,
           float* __restrict__ fbuf) {
    __shared__ __align__(16) float xb[72 * 20];
    __shared__ __align__(16) float h1l[128 * 20];
    __shared__ __align__(16) float h2l[128 * 20];

    const int tid = threadIdx.x;
    const int u = tid & 127;
    const int w0 = (tid >> 7) * 8;
    const int bx = blockIdx.x;
    const int seq = bx >> 7;
    const int wbase = (bx & 127) << 4;
    const float* xp = seq ? Y : X;

    const float* wih1 = wt;
    const float* whh1 = wt + 27648;
    const float* wih2 = wt + 76800;
    const float* whh2 = wt + 125952;

    const float br1  = bih1[u] + bhh1[u];
    const float bz1  = bih1[128 + u] + bhh1[128 + u];
    const float bni1 = bih1[256 + u];
    const float bnh1 = bhh1[256 + u];
    const float br2  = bih2[u] + bhh2[u];
    const float bz2  = bih2[128 + u] + bhh2[128 + u];
    const float bni2 = bih2[256 + u];
    const float bnh2 = bhh2[256 + u];

    float h1r[8], h2r[8];
#pragma unroll
    for (int j = 0; j < 8; ++j) { h1r[j] = 0.f; h2r[j] = 0.f; }
    for (int e = tid; e < 128 * 20; e += 256) { h1l[e] = 0.f; h2l[e] = 0.f; }
    __syncthreads();

    for (int t = 0; t < 8; ++t) {
        for (int e = tid; e < 72 * 16; e += 256) {
            int k = e >> 4, w = e & 15;
            int jj = k / 3, c = k - jj * 3;
            xb[k * 20 + w] = xp[jj * (3 * T_LEN) + c * T_LEN + ((wbase + w) << 2) + t];
        }
        __syncthreads();

        float ar[8], az[8], ai[8], ah[8];
#pragma unroll
        for (int j = 0; j < 8; ++j) { ar[j] = br1; az[j] = bz1; ai[j] = bni1; ah[j] = bnh1; }
        for (int k = 0; k < 72; ++k) {
            float wr = wih1[k * 384 + u];
            float wz = wih1[k * 384 + 128 + u];
            float wn = wih1[k * 384 + 256 + u];
            const float4 x0 = *(const float4*)&xb[k * 20 + w0];
            const float4 x1 = *(const float4*)&xb[k * 20 + w0 + 4];
            float xv[8] = {x0.x, x0.y, x0.z, x0.w, x1.x, x1.y, x1.z, x1.w};
#pragma unroll
            for (int j = 0; j < 8; ++j) {
                ar[j] = fmaf(wr, xv[j], ar[j]);
                az[j] = fmaf(wz, xv[j], az[j]);
                ai[j] = fmaf(wn, xv[j], ai[j]);
            }
        }
        for (int k = 0; k < 128; ++k) {
            float wr = whh1[k * 384 + u];
            float wz = whh1[k * 384 + 128 + u];
            float wn = whh1[k * 384 + 256 + u];
            const float4 x0 = *(const float4*)&h1l[k * 20 + w0];
            const float4 x1 = *(const float4*)&h1l[k * 20 + w0 + 4];
            float xv[8] = {x0.x, x0.y, x0.z, x0.w, x1.x, x1.y, x1.z, x1.w};
#pragma unroll
            for (int j = 0; j < 8; ++j) {
                ar[j] = fmaf(wr, xv[j], ar[j]);
                az[j] = fmaf(wz, xv[j], az[j]);
                ah[j] = fmaf(wn, xv[j], ah[j]);
            }
        }
        __syncthreads();
#pragma unroll
        for (int j = 0; j < 8; ++j) {
            float r = sigm(ar[j]);
            float z = sigm(az[j]);
            float n = tanh_f(ai[j] + r * ah[j]);
            h1r[j] = (1.f - z) * n + z * h1r[j];
        }
#pragma unroll
        for (int j = 0; j < 8; ++j) h1l[u * 20 + w0 + j] = h1r[j];
        __syncthreads();

#pragma unroll
        for (int j = 0; j < 8; ++j) { ar[j] = br2; az[j] = bz2; ai[j] = bni2; ah[j] = bnh2; }
        for (int k = 0; k < 128; ++k) {
            float wr = wih2[k * 384 + u];
            float wz = wih2[k * 384 + 128 + u];
            float wn = wih2[k * 384 + 256 + u];
            const float4 x0 = *(const float4*)&h1l[k * 20 + w0];
            const float4 x1 = *(const float4*)&h1l[k * 20 + w0 + 4];
            float xv[8] = {x0.x, x0.y, x0.z, x0.w, x1.x, x1.y, x1.z, x1.w};
#pragma unroll
            for (int j = 0; j < 8; ++j) {
                ar[j] = fmaf(wr, xv[j], ar[j]);
                az[j] = fmaf(wz, xv[j], az[j]);
                ai[j] = fmaf(wn, xv[j], ai[j]);
            }
        }
        for (int k = 0; k < 128; ++k) {
            float wr = whh2[k * 384 + u];
            float wz = whh2[k * 384 + 128 + u];
            float wn = whh2[k * 384 + 256 + u];
            const float4 x0 = *(const float4*)&h2l[k * 20 + w0];
            const float4 x1 = *(const float4*)&h2l[k * 20 + w0 + 4];
            float xv[8] = {x0.x, x0.y, x0.z, x0.w, x1.x, x1.y, x1.z, x1.w};
#pragma unroll
            for (int j = 0; j < 8; ++j) {
                ar[j] = fmaf(wr, xv[j], ar[j]);
                az[j] = fmaf(wz, xv[j], az[j]);
                ah[j] = fmaf(wn, xv[j], ah[j]);
            }
        }
        __syncthreads();
#pragma unroll
        for (int j = 0; j < 8; ++j) {
            float r = sigm(ar[j]);
            float z = sigm(az[j]);
            float n = tanh_f(ai[j] + r * ah[j]);
            h2r[j] = (1.f - z) * n + z * h2r[j];
        }
#pragma unroll
        for (int j = 0; j < 8; ++j) h2l[u * 20 + w0 + j] = h2r[j];
        __syncthreads();
    }

    for (int idx = tid; idx < 16 * 30; idx += 256) {
        int w = idx / 30, ff = idx - w * 30;
        float acc = b1[ff];
        for (int k = 0; k < 128; ++k) acc = fmaf(h2l[k * 20 + w], W1[ff * 128 + k], acc);
        fbuf[(seq * 2048 + wbase + w) * 32 + ff] = acc;
    }
}

// ------------------------------------------- pairwise sqdist -> E = exp(-D), padded
__global__ __launch_bounds__(256)
void k_pair(const float* __restrict__ fbuf, float* __restrict__ Ep) {
    __shared__ float f1t[64 * 33];
    __shared__ float f2t[64 * 33];
    const int tid = threadIdx.x;
    const int i0 = blockIdx.y * 64, j0 = blockIdx.x * 64;
    for (int e = tid; e < 64 * 32; e += 256) {
        int r = e >> 5, c = e & 31;
        f1t[r * 33 + c] = fbuf[(i0 + r) * 32 + c];
        f2t[r * 33 + c] = fbuf[(2048 + j0 + r) * 32 + c];
    }
    __syncthreads();
    const int tx = tid & 15, ty = tid >> 4;
    float acc[4][4];
#pragma unroll
    for (int r = 0; r < 4; ++r)
#pragma unroll
        for (int c = 0; c < 4; ++c) acc[r][c] = 0.f;
    for (int k = 0; k < 30; ++k) {
        float a[4], b[4];
#pragma unroll
        for (int r = 0; r < 4; ++r) a[r] = f1t[(ty * 4 + r) * 33 + k];
#pragma unroll
        for (int c = 0; c < 4; ++c) b[c] = f2t[(tx * 4 + c) * 33 + k];
#pragma unroll
        for (int r = 0; r < 4; ++r)
#pragma unroll
            for (int c = 0; c < 4; ++c) {
                float d = a[r] - b[c];
                acc[r][c] = fmaf(d, d, acc[r][c]);
            }
    }
#pragma unroll
    for (int r = 0; r < 4; ++r) {
        float4 v = make_float4(__expf(-acc[r][0]), __expf(-acc[r][1]),
                               __expf(-acc[r][2]), __expf(-acc[r][3]));
        *(float4*)&Ep[(size_t)(i0 + ty * 4 + r) * PD_LD + PD_OFF + j0 + tx * 4] = v;
    }
}

// ------------------------------------------- softDTW wavefront, EXP-DOMAIN
// 8 blocks (separate CUs -- R5 showed same-CU wave pipelines livelock) x 64
// lanes; lane owns 4 rows (r0=256b+4*lane), processes 8 cols per macro-step.
// Cell update: W = E*(Wd+Wu+Wl) -- 3 VALU, no transcendentals on the chain.
// Per-lane scale Sc (A_hat = Sc - log2 W), rescaled per macro via ldexp;
// capped at min(incoming)+100 so exp2 never overflows (avoids 0*inf=NaN);
// dead lanes (W==0) re-seed Sc from incoming boundary min.
// Lane->lane handoff: bottom-row values in log-domain via shfl_up.
// Band->band: R4-proven packed (tag<<32|f32) relaxed agent atomic-exchange,
// speculative loads + batched re-poll rounds.
#define DTW_MACRO(CUR, NXT, M)                                                   \
  {                                                                              \
    const int m = (M);                                                           \
    { /* prefetch next macro's E tile */                                         \
        int bs = 8 * (m + 1 - lane);                                             \
        bs = bs < -16 ? -16 : (bs > 2048 ? 2048 : bs);                           \
        _Pragma("unroll")                                                        \
        for (int r = 0; r < 4; ++r) {                                            \
            float4 lo = *(const float4*)(rp[r] + bs);                            \
            float4 hi = *(const float4*)(rp[r] + bs + 4);                        \
            NXT[r][0]=lo.x; NXT[r][1]=lo.y; NXT[r][2]=lo.z; NXT[r][3]=lo.w;      \
            NXT[r][4]=hi.x; NXT[r][5]=hi.y; NXT[r][6]=hi.z; NXT[r][7]=hi.w;      \
        }                                                                        \
    }                                                                            \
    uint64_t pvg[8];                                                             \
    if (b > 0 && lane == 0) {   /* speculative boundary loads for m+1 */         \
        _Pragma("unroll")                                                        \
        for (int u = 0; u < 8; ++u) {                                            \
            int jc = 8 * (m + 1) + u; jc = jc > 2047 ? 2047 : jc;                \
            pvg[u] = __hip_atomic_load(&bIn[jc], __ATOMIC_RELAXED,               \
                                       __HIP_MEMORY_SCOPE_AGENT);                \
        }                                                                        \
    }                                                                            \
    float Tw[8];                                                                 \
    _Pragma("unroll")                                                            \
    for (int c = 0; c < 8; ++c) Tw[c] = fexp2(Sc - sIn[c]);                      \
    float Td = fexp2(Sc - carryA);                                               \
    float blog[8];                                                               \
    _Pragma("unroll")                                                            \
    for (int c = 0; c < 8; ++c) {                                                \
        float up0 = Tw[c];                                                       \
        float dg0 = (c == 0) ? Td : Tw[c - 1];                                   \
        float w0 = CUR[0][c] * (dg0 + up0 + W0);                                 \
        float w1 = CUR[1][c] * (W0 + w0 + W1);                                   \
        float w2 = CUR[2][c] * (W1 + w1 + W2);                                   \
        float w3 = CUR[3][c] * (W2 + w2 + W3);                                   \
        W0 = w0; W1 = w1; W2 = w2; W3 = w3;                                      \
        blog[c] = fminf(Sc - flog2(w3), INF2);                                   \
    }                                                                            \
    carryA = sIn[7];                                                             \
    if (lane == 63) {                                                            \
        if (b < 7) {                                                             \
            _Pragma("unroll")                                                    \
            for (int c = 0; c < 8; ++c) {                                        \
                int j = 8 * (m - 63) + c;                                        \
                if (j >= 0 && j < 2048) {                                        \
                    uint64_t pk = ((uint64_t)(uint32_t)j << 32) |                \
                                  (uint64_t)__float_as_uint(blog[c]);            \
                    (void)__hip_atomic_exchange(&bOut[j], pk, __ATOMIC_RELAXED,  \
                                                __HIP_MEMORY_SCOPE_AGENT);       \
                }                                                                \
            }                                                                    \
        } else if (8 * (m - 63) + 7 == 2047) {                                   \
            res = blog[7];                                                       \
        }                                                                        \
    }                                                                            \
    float sh[8];                                                                 \
    _Pragma("unroll")                                                            \
    for (int c = 0; c < 8; ++c) sh[c] = __shfl_up(blog[c], 1);                   \
    if (lane > 0) {                                                              \
        _Pragma("unroll")                                                        \
        for (int c = 0; c < 8; ++c) sIn[c] = sh[c];                              \
    } else if (b == 0) {                                                         \
        _Pragma("unroll")                                                        \
        for (int c = 0; c < 8; ++c) sIn[c] = INF2;                               \
    } else {                                                                     \
        bool again = false;                                                      \
        _Pragma("unroll")                                                        \
        for (int u = 0; u < 8; ++u) {                                            \
            int jc = 8 * (m + 1) + u; jc = jc > 2047 ? 2047 : jc;                \
            if ((uint32_t)(pvg[u] >> 32) != (uint32_t)jc) again = true;          \
        }                                                                        \
        while (again) {   /* batched re-poll: 8 loads, one wait, check all */    \
            __builtin_amdgcn_s_sleep(2);                                         \
            _Pragma("unroll")                                                    \
            for (int u = 0; u < 8; ++u) {                                        \
                int jc = 8 * (m + 1) + u; jc = jc > 2047 ? 2047 : jc;            \
                pvg[u] = __hip_atomic_load(&bIn[jc], __ATOMIC_RELAXED,           \
                                           __HIP_MEMORY_SCOPE_AGENT);            \
            }                                                                    \
            again = false;                                                       \
            _Pragma("unroll")                                                    \
            for (int u = 0; u < 8; ++u) {                                        \
                int jc = 8 * (m + 1) + u; jc = jc > 2047 ? 2047 : jc;            \
                if ((uint32_t)(pvg[u] >> 32) != (uint32_t)jc) again = true;      \
            }                                                                    \
        }                                                                        \
        _Pragma("unroll")                                                        \
        for (int u = 0; u < 8; ++u) sIn[u] = __uint_as_float((uint32_t)pvg[u]);  \
    }                                                                            \
    { /* scale update (uses NEXT macro's incoming mins) */                       \
        float mn = sIn[0];                                                       \
        _Pragma("unroll")                                                        \
        for (int c = 1; c < 8; ++c) mn = fminf(mn, sIn[c]);                      \
        float wmax = fmaxf(fmaxf(W0, W1), fmaxf(W2, W3));                        \
        float Sc_new;                                                            \
        if (wmax > 0.f) {                                                        \
            int e = (int)((__float_as_uint(wmax) >> 23) & 0xFFu) - 127;          \
            Sc_new = fminf(Sc - (float)e, mn + 100.f);                           \
        } else {                                                                 \
            Sc_new = fminf(mn, 1e9f);                                            \
        }                                                                        \
        int dd = (int)fmaxf(fminf(Sc_new - Sc, 999.f), -999.f);                  \
        W0 = ldexpf(W0, dd); W1 = ldexpf(W1, dd);                                \
        W2 = ldexpf(W2, dd); W3 = ldexpf(W3, dd);                                \
        Sc = Sc_new;                                                             \
    }                                                                            \
  }

__global__ __launch_bounds__(64)
void k_dtw(const float* __restrict__ Ep, uint64_t* bndG, float* __restrict__ out) {
    const int b = blockIdx.x;
    const int lane = threadIdx.x;
    const int r0 = b * 256 + lane * 4;
    const uint64_t* bIn = bndG + (size_t)(b - 1) * 2048;
    uint64_t* bOut = bndG + (size_t)b * 2048;

    const float* rp[4];
#pragma unroll
    for (int r = 0; r < 4; ++r) rp[r] = Ep + (size_t)(r0 + r) * PD_LD + PD_OFF;

    float W0 = 0.f, W1 = 0.f, W2 = 0.f, W3 = 0.f;
    float Sc = 0.f;
    float carryA = (b == 0 && lane == 0) ? 0.f : INF2;  // seed: A(-1,-1)=0
    float res = 0.f;
    float sIn[8];
#pragma unroll
    for (int c = 0; c < 8; ++c) sIn[c] = INF2;

    float eA[4][8], eB[4][8];
    {   // preload macro-0 tile
        int bs = 8 * (0 - lane);
        bs = bs < -16 ? -16 : bs;
#pragma unroll
        for (int r = 0; r < 4; ++r) {
            float4 lo = *(const float4*)(rp[r] + bs);
            float4 hi = *(const float4*)(rp[r] + bs + 4);
            eA[r][0]=lo.x; eA[r][1]=lo.y; eA[r][2]=lo.z; eA[r][3]=lo.w;
            eA[r][4]=hi.x; eA[r][5]=hi.y; eA[r][6]=hi.z; eA[r][7]=hi.w;
        }
    }

    if (b > 0 && lane == 0) {   // blocking pre-poll for macro-0 boundary cols 0..7
        uint64_t pv[8];
        bool again = true;
        while (again) {
#pragma unroll
            for (int u = 0; u < 8; ++u)
                pv[u] = __hip_atomic_load(&bIn[u], __ATOMIC_RELAXED,
                                          __HIP_MEMORY_SCOPE_AGENT);
            again = false;
#pragma unroll
            for (int u = 0; u < 8; ++u)
                if ((uint32_t)(pv[u] >> 32) != (uint32_t)u) again = true;
            if (again) __builtin_amdgcn_s_sleep(2);
        }
        float mn = INF2;
#pragma unroll
        for (int u = 0; u < 8; ++u) {
            sIn[u] = __uint_as_float((uint32_t)pv[u]);
            mn = fminf(mn, sIn[u]);
        }
        Sc = fminf(mn, 1e9f);   // align scale with incoming so macro 0 survives
    }

    // 320 macro-steps of 8 cols cover all cols; lane63 hits col 2047 at m=318
    for (int mm = 0; mm < 320; mm += 2) {
        DTW_MACRO(eA, eB, mm);
        DTW_MACRO(eB, eA, mm + 1);
    }

    if (b == 7 && lane == 63) out[0] = res * LN2;   // back to base-e units
}

// ------------------------------------------- launch
extern "C" void kernel_launch(void* const* d_in, const int* in_sizes, int n_in,
                              void* d_out, int out_size, void* d_ws, size_t ws_size,
                              hipStream_t stream) {
    const float* X    = (const float*)d_in[0];
    const float* Y    = (const float*)d_in[1];
    const float* Wih1 = (const float*)d_in[2];
    const float* Whh1 = (const float*)d_in[3];
    const float* bih1 = (const float*)d_in[4];
    const float* bhh1 = (const float*)d_in[5];
    const float* Wih2 = (const float*)d_in[6];
    const float* Whh2 = (const float*)d_in[7];
    const float* bih2 = (const float*)d_in[8];
    const float* bhh2 = (const float*)d_in[9];
    const float* W1   = (const float*)d_in[10];
    const float* b1   = (const float*)d_in[11];
    float* out = (float*)d_out;

    // Layout (floats). wt overlaps Ep's tail (dead after k_gru; k_pair
    // overwrites all of Ep afterwards). ~17.7 MB total.
    float* ws   = (float*)d_ws;
    float* fbuf = ws;                            // 131072 floats
    uint64_t* bndG = (uint64_t*)(ws + 131072);   // 7*2048 u64 = 28672 floats
    float* Ep   = ws + 131072 + 28672;           // 2048*2080 = 4259840 floats
    float* wt   = Ep + 4259840 - 175104;         // overlapped tail

    k_prep<<<684, 256, 0, stream>>>(Wih1, Whh1, Wih2, Whh2, wt);
    k_gru<<<256, 256, 0, stream>>>(X, Y, wt, bih1, bhh1, bih2, bhh2, W1, b1, fbuf);
    k_pair<<<dim3(32, 32), 256, 0, stream>>>(fbuf, Ep);
    k_dtw<<<8, 64, 0, stream>>>(Ep, bndG, out);
}

// Round 7
// 1015.866 us; speedup vs baseline: 2.4200x; 1.3772x over previous
//
#include <hip/hip_runtime.h>
#include <stdint.h>

#define T_LEN 8196
#define LOG2E 1.4426950408889634f
#define LN2   0.6931471805599453f
#define INF2  1.4426950e10f   /* 1e10 * log2(e): INF in base-2-scaled units */
#define PD_LD 2080            /* padded E row stride: 16 left + 2048 + 16 right */
#define PD_OFF 16

// ---------------------------------------------------------------- helpers
__device__ __forceinline__ float fexp2(float x) {
#if __has_builtin(__builtin_amdgcn_exp2f)
    return __builtin_amdgcn_exp2f(x);
#else
    return __expf(x * LN2);
#endif
}
__device__ __forceinline__ float flog2(float x) {
#if __has_builtin(__builtin_amdgcn_logf)
    return __builtin_amdgcn_logf(x);   // v_log_f32 is base-2
#else
    return __logf(x) * LOG2E;
#endif
}
__device__ __forceinline__ float sigm(float x) { return 1.0f / (1.0f + __expf(-x)); }
__device__ __forceinline__ float tanh_f(float x) {
    x = fminf(fmaxf(x, -15.0f), 15.0f);
    float e = __expf(2.0f * x);
    return (e - 1.0f) / (e + 1.0f);
}

// ------------------------------------------- prep: transpose weights
__global__ void k_prep(const float* __restrict__ Wih1, const float* __restrict__ Whh1,
                       const float* __restrict__ Wih2, const float* __restrict__ Whh2,
                       float* __restrict__ wt) {
    int gid = blockIdx.x * 256 + threadIdx.x;
    if (gid >= 175104) return;
    if (gid < 27648) {
        int k = gid / 384, g = gid % 384;
        wt[gid] = Wih1[g * 72 + k];
    } else if (gid < 76800) {
        int r = gid - 27648; int k = r / 384, g = r % 384;
        wt[gid] = Whh1[g * 128 + k];
    } else if (gid < 125952) {
        int r = gid - 76800; int k = r / 384, g = r % 384;
        wt[gid] = Wih2[g * 128 + k];
    } else {
        int r = gid - 125952; int k = r / 384, g = r % 384;
        wt[gid] = Whh2[g * 128 + k];
    }
}

// ------------------------------------------- GRU features (unchanged)
__global__ __launch_bounds__(256)
void k_gru(const float* __restrict__ X, const float* __restrict__ Y,
           const float* __restrict__ wt,
           const float* __restrict__ bih1, const float* __restrict__ bhh1,
           const float* __restrict__ bih2, const float* __restrict__ bhh2,
           const float* __restrict__ W1, const float* __restrict__ b1,
           float* __restrict__ fbuf) {
    __shared__ __align__(16) float xb[72 * 20];
    __shared__ __align__(16) float h1l[128 * 20];
    __shared__ __align__(16) float h2l[128 * 20];

    const int tid = threadIdx.x;
    const int u = tid & 127;
    const int w0 = (tid >> 7) * 8;
    const int bx = blockIdx.x;
    const int seq = bx >> 7;
    const int wbase = (bx & 127) << 4;
    const float* xp = seq ? Y : X;

    const float* wih1 = wt;
    const float* whh1 = wt + 27648;
    const float* wih2 = wt + 76800;
    const float* whh2 = wt + 125952;

    const float br1  = bih1[u] + bhh1[u];
    const float bz1  = bih1[128 + u] + bhh1[128 + u];
    const float bni1 = bih1[256 + u];
    const float bnh1 = bhh1[256 + u];
    const float br2  = bih2[u] + bhh2[u];
    const float bz2  = bih2[128 + u] + bhh2[128 + u];
    const float bni2 = bih2[256 + u];
    const float bnh2 = bhh2[256 + u];

    float h1r[8], h2r[8];
#pragma unroll
    for (int j = 0; j < 8; ++j) { h1r[j] = 0.f; h2r[j] = 0.f; }
    for (int e = tid; e < 128 * 20; e += 256) { h1l[e] = 0.f; h2l[e] = 0.f; }
    __syncthreads();

    for (int t = 0; t < 8; ++t) {
        for (int e = tid; e < 72 * 16; e += 256) {
            int k = e >> 4, w = e & 15;
            int jj = k / 3, c = k - jj * 3;
            xb[k * 20 + w] = xp[jj * (3 * T_LEN) + c * T_LEN + ((wbase + w) << 2) + t];
        }
        __syncthreads();

        float ar[8], az[8], ai[8], ah[8];
#pragma unroll
        for (int j = 0; j < 8; ++j) { ar[j] = br1; az[j] = bz1; ai[j] = bni1; ah[j] = bnh1; }
        for (int k = 0; k < 72; ++k) {
            float wr = wih1[k * 384 + u];
            float wz = wih1[k * 384 + 128 + u];
            float wn = wih1[k * 384 + 256 + u];
            const float4 x0 = *(const float4*)&xb[k * 20 + w0];
            const float4 x1 = *(const float4*)&xb[k * 20 + w0 + 4];
            float xv[8] = {x0.x, x0.y, x0.z, x0.w, x1.x, x1.y, x1.z, x1.w};
#pragma unroll
            for (int j = 0; j < 8; ++j) {
                ar[j] = fmaf(wr, xv[j], ar[j]);
                az[j] = fmaf(wz, xv[j], az[j]);
                ai[j] = fmaf(wn, xv[j], ai[j]);
            }
        }
        for (int k = 0; k < 128; ++k) {
            float wr = whh1[k * 384 + u];
            float wz = whh1[k * 384 + 128 + u];
            float wn = whh1[k * 384 + 256 + u];
            const float4 x0 = *(const float4*)&h1l[k * 20 + w0];
            const float4 x1 = *(const float4*)&h1l[k * 20 + w0 + 4];
            float xv[8] = {x0.x, x0.y, x0.z, x0.w, x1.x, x1.y, x1.z, x1.w};
#pragma unroll
            for (int j = 0; j < 8; ++j) {
                ar[j] = fmaf(wr, xv[j], ar[j]);
                az[j] = fmaf(wz, xv[j], az[j]);
                ah[j] = fmaf(wn, xv[j], ah[j]);
            }
        }
        __syncthreads();
#pragma unroll
        for (int j = 0; j < 8; ++j) {
            float r = sigm(ar[j]);
            float z = sigm(az[j]);
            float n = tanh_f(ai[j] + r * ah[j]);
            h1r[j] = (1.f - z) * n + z * h1r[j];
        }
#pragma unroll
        for (int j = 0; j < 8; ++j) h1l[u * 20 + w0 + j] = h1r[j];
        __syncthreads();

#pragma unroll
        for (int j = 0; j < 8; ++j) { ar[j] = br2; az[j] = bz2; ai[j] = bni2; ah[j] = bnh2; }
        for (int k = 0; k < 128; ++k) {
            float wr = wih2[k * 384 + u];
            float wz = wih2[k * 384 + 128 + u];
            float wn = wih2[k * 384 + 256 + u];
            const float4 x0 = *(const float4*)&h1l[k * 20 + w0];
            const float4 x1 = *(const float4*)&h1l[k * 20 + w0 + 4];
            float xv[8] = {x0.x, x0.y, x0.z, x0.w, x1.x, x1.y, x1.z, x1.w};
#pragma unroll
            for (int j = 0; j < 8; ++j) {
                ar[j] = fmaf(wr, xv[j], ar[j]);
                az[j] = fmaf(wz, xv[j], az[j]);
                ai[j] = fmaf(wn, xv[j], ai[j]);
            }
        }
        for (int k = 0; k < 128; ++k) {
            float wr = whh2[k * 384 + u];
            float wz = whh2[k * 384 + 128 + u];
            float wn = whh2[k * 384 + 256 + u];
            const float4 x0 = *(const float4*)&h2l[k * 20 + w0];
            const float4 x1 = *(const float4*)&h2l[k * 20 + w0 + 4];
            float xv[8] = {x0.x, x0.y, x0.z, x0.w, x1.x, x1.y, x1.z, x1.w};
#pragma unroll
            for (int j = 0; j < 8; ++j) {
                ar[j] = fmaf(wr, xv[j], ar[j]);
                az[j] = fmaf(wz, xv[j], az[j]);
                ah[j] = fmaf(wn, xv[j], ah[j]);
            }
        }
        __syncthreads();
#pragma unroll
        for (int j = 0; j < 8; ++j) {
            float r = sigm(ar[j]);
            float z = sigm(az[j]);
            float n = tanh_f(ai[j] + r * ah[j]);
            h2r[j] = (1.f - z) * n + z * h2r[j];
        }
#pragma unroll
        for (int j = 0; j < 8; ++j) h2l[u * 20 + w0 + j] = h2r[j];
        __syncthreads();
    }

    for (int idx = tid; idx < 16 * 30; idx += 256) {
        int w = idx / 30, ff = idx - w * 30;
        float acc = b1[ff];
        for (int k = 0; k < 128; ++k) acc = fmaf(h2l[k * 20 + w], W1[ff * 128 + k], acc);
        fbuf[(seq * 2048 + wbase + w) * 32 + ff] = acc;
    }
}

// ------------------------------------------- pairwise sqdist -> E = exp(-D), padded
__global__ __launch_bounds__(256)
void k_pair(const float* __restrict__ fbuf, float* __restrict__ Ep) {
    __shared__ float f1t[64 * 33];
    __shared__ float f2t[64 * 33];
    const int tid = threadIdx.x;
    const int i0 = blockIdx.y * 64, j0 = blockIdx.x * 64;
    for (int e = tid; e < 64 * 32; e += 256) {
        int r = e >> 5, c = e & 31;
        f1t[r * 33 + c] = fbuf[(i0 + r) * 32 + c];
        f2t[r * 33 + c] = fbuf[(2048 + j0 + r) * 32 + c];
    }
    __syncthreads();
    const int tx = tid & 15, ty = tid >> 4;
    float acc[4][4];
#pragma unroll
    for (int r = 0; r < 4; ++r)
#pragma unroll
        for (int c = 0; c < 4; ++c) acc[r][c] = 0.f;
    for (int k = 0; k < 30; ++k) {
        float a[4], b[4];
#pragma unroll
        for (int r = 0; r < 4; ++r) a[r] = f1t[(ty * 4 + r) * 33 + k];
#pragma unroll
        for (int c = 0; c < 4; ++c) b[c] = f2t[(tx * 4 + c) * 33 + k];
#pragma unroll
        for (int r = 0; r < 4; ++r)
#pragma unroll
            for (int c = 0; c < 4; ++c) {
                float d = a[r] - b[c];
                acc[r][c] = fmaf(d, d, acc[r][c]);
            }
    }
#pragma unroll
    for (int r = 0; r < 4; ++r) {
        float4 v = make_float4(__expf(-acc[r][0]), __expf(-acc[r][1]),
                               __expf(-acc[r][2]), __expf(-acc[r][3]));
        *(float4*)&Ep[(size_t)(i0 + ty * 4 + r) * PD_LD + PD_OFF + j0 + tx * 4] = v;
    }
}

// ------------------------------------------- softDTW wavefront, EXP-DOMAIN
// 8 blocks x 64 lanes; lane owns 4 rows, 8 cols per macro (R6 shape).
// R7 changes (latency plumbing only -- R6 stalled ~2600 cyc/macro):
//  * E tiles TRIPLE-buffered: prefetch for m+2 issued at m (~2.8T in flight
//    vs R6's ~1T < 900-cyc HBM latency).
//  * Boundary ring 3-deep (pvs0/1/2): agent loads for macro m+3 issued at m,
//    tag-verified (VALU only) when consumed at end of m+2.
//  * 64-col startup SLACK + s_sleep(32) backoff on verify failure: consumer
//    sits ~8 macros behind the frontier instead of marginal-failure polling.
#define DTW_MACRO(CUR, PF, PVC, PVI, M)                                          \
  {                                                                              \
    const int m = (M);                                                           \
    { /* prefetch E tile for macro m+2 */                                        \
        int bs = 8 * (m + 2 - lane);                                             \
        bs = bs < -16 ? -16 : (bs > 2048 ? 2048 : bs);                           \
        _Pragma("unroll")                                                        \
        for (int r = 0; r < 4; ++r) {                                            \
            float4 lo = *(const float4*)(rp[r] + bs);                            \
            float4 hi = *(const float4*)(rp[r] + bs + 4);                        \
            PF[r][0]=lo.x; PF[r][1]=lo.y; PF[r][2]=lo.z; PF[r][3]=lo.w;          \
            PF[r][4]=hi.x; PF[r][5]=hi.y; PF[r][6]=hi.z; PF[r][7]=hi.w;          \
        }                                                                        \
    }                                                                            \
    if (b > 0 && lane == 0) {   /* issue boundary loads for macro m+3 */         \
        _Pragma("unroll")                                                        \
        for (int u = 0; u < 8; ++u) {                                            \
            int jc = 8 * (m + 3) + u; jc = jc > 2047 ? 2047 : jc;                \
            PVI[u] = __hip_atomic_load(&bIn[jc], __ATOMIC_RELAXED,               \
                                       __HIP_MEMORY_SCOPE_AGENT);                \
        }                                                                        \
    }                                                                            \
    float Tw[8];                                                                 \
    _Pragma("unroll")                                                            \
    for (int c = 0; c < 8; ++c) Tw[c] = fexp2(Sc - sIn[c]);                      \
    float Td = fexp2(Sc - carryA);                                               \
    float blog[8];                                                               \
    _Pragma("unroll")                                                            \
    for (int c = 0; c < 8; ++c) {                                                \
        float up0 = Tw[c];                                                       \
        float dg0 = (c == 0) ? Td : Tw[c - 1];                                   \
        float w0 = CUR[0][c] * (dg0 + up0 + W0);                                 \
        float w1 = CUR[1][c] * (W0 + w0 + W1);                                   \
        float w2 = CUR[2][c] * (W1 + w1 + W2);                                   \
        float w3 = CUR[3][c] * (W2 + w2 + W3);                                   \
        W0 = w0; W1 = w1; W2 = w2; W3 = w3;                                      \
        blog[c] = fminf(Sc - flog2(w3), INF2);                                   \
    }                                                                            \
    carryA = sIn[7];                                                             \
    if (lane == 63) {                                                            \
        if (b < 7) {                                                             \
            _Pragma("unroll")                                                    \
            for (int c = 0; c < 8; ++c) {                                        \
                int j = 8 * (m - 63) + c;                                        \
                if (j >= 0 && j < 2048) {                                        \
                    uint64_t pk = ((uint64_t)(uint32_t)j << 32) |                \
                                  (uint64_t)__float_as_uint(blog[c]);            \
                    (void)__hip_atomic_exchange(&bOut[j], pk, __ATOMIC_RELAXED,  \
                                                __HIP_MEMORY_SCOPE_AGENT);       \
                }                                                                \
            }                                                                    \
        } else if (8 * (m - 63) + 7 == 2047) {                                   \
            res = blog[7];                                                       \
        }                                                                        \
    }                                                                            \
    float sh[8];                                                                 \
    _Pragma("unroll")                                                            \
    for (int c = 0; c < 8; ++c) sh[c] = __shfl_up(blog[c], 1);                   \
    if (lane > 0) {                                                              \
        _Pragma("unroll")                                                        \
        for (int c = 0; c < 8; ++c) sIn[c] = sh[c];                              \
    } else if (b == 0) {                                                         \
        _Pragma("unroll")                                                        \
        for (int c = 0; c < 8; ++c) sIn[c] = INF2;                               \
    } else {   /* consume ring slot PVC = boundary for macro m+1 */              \
        bool again = false;                                                      \
        _Pragma("unroll")                                                        \
        for (int u = 0; u < 8; ++u) {                                            \
            int jc = 8 * (m + 1) + u; jc = jc > 2047 ? 2047 : jc;                \
            if ((uint32_t)(PVC[u] >> 32) != (uint32_t)jc) again = true;          \
        }                                                                        \
        while (again) {   /* rare: fell on frontier; long backoff */             \
            __builtin_amdgcn_s_sleep(32);                                        \
            _Pragma("unroll")                                                    \
            for (int u = 0; u < 8; ++u) {                                        \
                int jc = 8 * (m + 1) + u; jc = jc > 2047 ? 2047 : jc;            \
                PVC[u] = __hip_atomic_load(&bIn[jc], __ATOMIC_RELAXED,           \
                                           __HIP_MEMORY_SCOPE_AGENT);            \
            }                                                                    \
            again = false;                                                       \
            _Pragma("unroll")                                                    \
            for (int u = 0; u < 8; ++u) {                                        \
                int jc = 8 * (m + 1) + u; jc = jc > 2047 ? 2047 : jc;            \
                if ((uint32_t)(PVC[u] >> 32) != (uint32_t)jc) again = true;      \
            }                                                                    \
        }                                                                        \
        _Pragma("unroll")                                                        \
        for (int u = 0; u < 8; ++u) sIn[u] = __uint_as_float((uint32_t)PVC[u]);  \
    }                                                                            \
    { /* scale update (uses NEXT macro's incoming mins) */                       \
        float mn = sIn[0];                                                       \
        _Pragma("unroll")                                                        \
        for (int c = 1; c < 8; ++c) mn = fminf(mn, sIn[c]);                      \
        float wmax = fmaxf(fmaxf(W0, W1), fmaxf(W2, W3));                        \
        float Sc_new;                                                            \
        if (wmax > 0.f) {                                                        \
            int e = (int)((__float_as_uint(wmax) >> 23) & 0xFFu) - 127;          \
            Sc_new = fminf(Sc - (float)e, mn + 100.f);                           \
        } else {                                                                 \
            Sc_new = fminf(mn, 1e9f);                                            \
        }                                                                        \
        int dd = (int)fmaxf(fminf(Sc_new - Sc, 999.f), -999.f);                  \
        W0 = ldexpf(W0, dd); W1 = ldexpf(W1, dd);                                \
        W2 = ldexpf(W2, dd); W3 = ldexpf(W3, dd);                                \
        Sc = Sc_new;                                                             \
    }                                                                            \
  }

__global__ __launch_bounds__(64)
void k_dtw(const float* __restrict__ Ep, uint64_t* bndG, float* __restrict__ out) {
    const int b = blockIdx.x;
    const int lane = threadIdx.x;
    const int r0 = b * 256 + lane * 4;
    const uint64_t* bIn = bndG + (size_t)(b - 1) * 2048;
    uint64_t* bOut = bndG + (size_t)b * 2048;

    const float* rp[4];
#pragma unroll
    for (int r = 0; r < 4; ++r) rp[r] = Ep + (size_t)(r0 + r) * PD_LD + PD_OFF;

    float W0 = 0.f, W1 = 0.f, W2 = 0.f, W3 = 0.f;
    float Sc = 0.f;
    float carryA = (b == 0 && lane == 0) ? 0.f : INF2;  // seed: A(-1,-1)=0
    float res = 0.f;
    float sIn[8];
#pragma unroll
    for (int c = 0; c < 8; ++c) sIn[c] = INF2;

    uint64_t pvs0[8], pvs1[8], pvs2[8];

    if (b > 0 && lane == 0) {
        // --- startup SLACK: wait until producer is ~64 cols past our need
        {
            uint64_t p = __hip_atomic_load(&bIn[71], __ATOMIC_RELAXED,
                                           __HIP_MEMORY_SCOPE_AGENT);
            while ((uint32_t)(p >> 32) != 71u) {
                __builtin_amdgcn_s_sleep(8);
                p = __hip_atomic_load(&bIn[71], __ATOMIC_RELAXED,
                                      __HIP_MEMORY_SCOPE_AGENT);
            }
        }
        // --- blocking poll for macro-0 boundary (cols 0..7) + scale seed
        uint64_t pv[8];
        bool again = true;
        while (again) {
#pragma unroll
            for (int u = 0; u < 8; ++u)
                pv[u] = __hip_atomic_load(&bIn[u], __ATOMIC_RELAXED,
                                          __HIP_MEMORY_SCOPE_AGENT);
            again = false;
#pragma unroll
            for (int u = 0; u < 8; ++u)
                if ((uint32_t)(pv[u] >> 32) != (uint32_t)u) again = true;
            if (again) __builtin_amdgcn_s_sleep(2);
        }
        float mn = INF2;
#pragma unroll
        for (int u = 0; u < 8; ++u) {
            sIn[u] = __uint_as_float((uint32_t)pv[u]);
            mn = fminf(mn, sIn[u]);
        }
        Sc = fminf(mn, 1e9f);
        // --- prime ring: targets macro 1 (cols 8..15) and macro 2 (16..23)
#pragma unroll
        for (int u = 0; u < 8; ++u)
            pvs1[u] = __hip_atomic_load(&bIn[8 + u], __ATOMIC_RELAXED,
                                        __HIP_MEMORY_SCOPE_AGENT);
#pragma unroll
        for (int u = 0; u < 8; ++u)
            pvs2[u] = __hip_atomic_load(&bIn[16 + u], __ATOMIC_RELAXED,
                                        __HIP_MEMORY_SCOPE_AGENT);
    }

    float eT0[4][8], eT1[4][8], eT2[4][8];
#pragma unroll
    for (int tt = 0; tt < 2; ++tt) {   // preload tiles for macros 0 and 1
        int bs = 8 * (tt - lane);
        bs = bs < -16 ? -16 : bs;
#pragma unroll
        for (int r = 0; r < 4; ++r) {
            float4 lo = *(const float4*)(rp[r] + bs);
            float4 hi = *(const float4*)(rp[r] + bs + 4);
            float (*dst)[8] = tt ? eT1 : eT0;
            dst[r][0]=lo.x; dst[r][1]=lo.y; dst[r][2]=lo.z; dst[r][3]=lo.w;
            dst[r][4]=hi.x; dst[r][5]=hi.y; dst[r][6]=hi.z; dst[r][7]=hi.w;
        }
    }

    // 321 macro-steps of 8 cols (lane63 hits col 2047 at m=318)
    for (int mm = 0; mm < 321; mm += 3) {
        DTW_MACRO(eT0, eT2, pvs1, pvs0, mm);
        DTW_MACRO(eT1, eT0, pvs2, pvs1, mm + 1);
        DTW_MACRO(eT2, eT1, pvs0, pvs2, mm + 2);
    }

    if (b == 7 && lane == 63) out[0] = res * LN2;   // back to base-e units
}

// ------------------------------------------- launch
extern "C" void kernel_launch(void* const* d_in, const int* in_sizes, int n_in,
                              void* d_out, int out_size, void* d_ws, size_t ws_size,
                              hipStream_t stream) {
    const float* X    = (const float*)d_in[0];
    const float* Y    = (const float*)d_in[1];
    const float* Wih1 = (const float*)d_in[2];
    const float* Whh1 = (const float*)d_in[3];
    const float* bih1 = (const float*)d_in[4];
    const float* bhh1 = (const float*)d_in[5];
    const float* Wih2 = (const float*)d_in[6];
    const float* Whh2 = (const float*)d_in[7];
    const float* bih2 = (const float*)d_in[8];
    const float* bhh2 = (const float*)d_in[9];
    const float* W1   = (const float*)d_in[10];
    const float* b1   = (const float*)d_in[11];
    float* out = (float*)d_out;

    // Layout (floats). wt overlaps Ep's tail (dead after k_gru; k_pair
    // overwrites all of Ep afterwards). ~17.7 MB total.
    float* ws   = (float*)d_ws;
    float* fbuf = ws;                            // 131072 floats
    uint64_t* bndG = (uint64_t*)(ws + 131072);   // 7*2048 u64 = 28672 floats
    float* Ep   = ws + 131072 + 28672;           // 2048*2080 = 4259840 floats
    float* wt   = Ep + 4259840 - 175104;         // overlapped tail

    k_prep<<<684, 256, 0, stream>>>(Wih1, Whh1, Wih2, Whh2, wt);
    k_gru<<<256, 256, 0, stream>>>(X, Y, wt, bih1, bhh1, bih2, bhh2, W1, b1, fbuf);
    k_pair<<<dim3(32, 32), 256, 0, stream>>>(fbuf, Ep);
    k_dtw<<<8, 64, 0, stream>>>(Ep, bndG, out);
}